// Round 6
// baseline (1337.523 us; speedup 1.0000x reference)
//
#include <hip/hip_runtime.h>
#include <hip/hip_bf16.h>
#include <stdint.h>

#define E_DIM 128
#define L_SEQ 512
#define B_SZ  128

typedef _Float16 h2 __attribute__((ext_vector_type(2)));
typedef _Float16 f16x8 __attribute__((ext_vector_type(8)));
typedef float f32x4 __attribute__((ext_vector_type(4)));

// ---------------- workspace layout (bytes) ----------------
constexpr size_t SZ_W12  = 512 * 128 * 4;                 // 256 KB
constexpr size_t SZ_TQ   = (size_t)10001 * 128 * 2 * 4;   // (q2,q3) pairs
constexpr size_t SZ_TC   = (size_t)301 * 128 * 2 * 4;
constexpr size_t SZ_TSD  = (size_t)200 * 128 * 4 * 4;     // (sd2,sd3,sd6,pad)
constexpr size_t SZ_TQD  = (size_t)200 * 128 * 4 * 4;
constexpr size_t SZ_TA45 = (size_t)20002 * 128 * 2 * 4;   // (a4,a5)
constexpr size_t SZ_TA6  = (size_t)20002 * 128 * 4;
constexpr size_t SZ_K    = (size_t)B_SZ * L_SEQ * 128 * 4; // 33.5 MB
constexpr size_t SZ_WP   = (size_t)5 * 64 * 128 * 4;      // packed f16-pair weights

constexpr size_t OFF_W12  = 0;
constexpr size_t OFF_W13  = OFF_W12 + SZ_W12;
constexpr size_t OFF_BV2  = OFF_W13 + SZ_W12;
constexpr size_t OFF_BV3  = OFF_BV2 + 512;
constexpr size_t OFF_TQ   = OFF_BV3 + 512;
constexpr size_t OFF_TC   = OFF_TQ + SZ_TQ;
constexpr size_t OFF_TSD  = OFF_TC + SZ_TC;
constexpr size_t OFF_TQD  = OFF_TSD + SZ_TSD;
constexpr size_t OFF_TA45 = OFF_TQD + SZ_TQD;
constexpr size_t OFF_TA6  = OFF_TA45 + SZ_TA45;
constexpr size_t OFF_K    = OFF_TA6 + SZ_TA6;
constexpr size_t OFF_WP   = OFF_K + SZ_K;                 // total ~76.3 MB

// ---------------- helpers ----------------
__device__ __forceinline__ float fdot2f(unsigned int a, unsigned int b, float c) {
#if __has_builtin(__builtin_amdgcn_fdot2)
  return __builtin_amdgcn_fdot2(__builtin_bit_cast(h2, a), __builtin_bit_cast(h2, b), c, false);
#else
  h2 x = __builtin_bit_cast(h2, a), y = __builtin_bit_cast(h2, b);
  return c + (float)x[0] * (float)y[0] + (float)x[1] * (float)y[1];
#endif
}

__device__ __forceinline__ unsigned int packh2(float a, float b) {
  h2 v; v[0] = (_Float16)a; v[1] = (_Float16)b;
  return __builtin_bit_cast(unsigned int, v);
}

__device__ __forceinline__ float fsig(float x) {
  float t = __builtin_amdgcn_exp2f(-1.4426950408889634f * x);
  return __builtin_amdgcn_rcpf(1.0f + t);
}
__device__ __forceinline__ float ftanh(float x) {
  float t = __builtin_amdgcn_exp2f(2.8853900817779268f * x);
  return 1.0f - 2.0f * __builtin_amdgcn_rcpf(t + 1.0f);
}

// LDS-only barrier: no vmcnt drain -> global prefetch stays in flight
#define BARRIER_RAW() asm volatile("s_waitcnt lgkmcnt(0)\n\ts_barrier" ::: "memory")

// ---------------- prep A: W12 = W1@W2, W13 = W1@W3 (2 rows/block) ----------------
__global__ __launch_bounds__(256, 2) void prepA_kernel(
    const float* __restrict__ W1, const float* __restrict__ W2, const float* __restrict__ W3,
    const float* __restrict__ b1, const float* __restrict__ b2, const float* __restrict__ b3,
    char* __restrict__ ws) {
  float* W12 = (float*)(ws + OFF_W12);
  float* W13 = (float*)(ws + OFF_W13);
  float* bv2 = (float*)(ws + OFF_BV2);
  float* bv3 = (float*)(ws + OFF_BV3);
  const int blk = blockIdx.x, tid = threadIdx.x;
  if (blk < 512) {
    const int m = blk >> 8;
    const int rp = blk & 255;
    const float* M = m ? W3 : W2;
    float* dst = m ? W13 : W12;
    const int rr = tid >> 7, j = tid & 127;
    const int r = rp * 2 + rr;
    __shared__ float rowL[2][128];
    rowL[rr][j] = W1[r * 128 + j];
    __syncthreads();
    float acc = 0.0f;
#pragma unroll 8
    for (int t = 0; t < 128; t++) acc += rowL[rr][t] * M[t * 128 + j];
    dst[r * 128 + j] = acc;
  } else if (tid < 128) {
    float a2 = b2[tid], a3 = b3[tid];
    for (int t = 0; t < 128; t++) {
      float bb = b1[t];
      a2 += bb * W2[t * 128 + tid];
      a3 += bb * W3[t * 128 + tid];
    }
    bv2[tid] = a2;
    bv3[tid] = a3;
  }
}

// ---------------- prep W: pack weight columns into f16-pair tables ----------------
// WP[mat][p][j] = packh2(W[2p][j], W[2p+1][j]); mat order: W2,W3,W4,W5,W6
__global__ __launch_bounds__(256, 2) void prepW_kernel(
    const float* __restrict__ W2, const float* __restrict__ W3, const float* __restrict__ W4,
    const float* __restrict__ W5, const float* __restrict__ W6, char* __restrict__ ws) {
  unsigned int* WP = (unsigned int*)(ws + OFF_WP);
  const float* src = (blockIdx.x == 0) ? W2 : (blockIdx.x == 1) ? W3 :
                     (blockIdx.x == 2) ? W4 : (blockIdx.x == 3) ? W5 : W6;
  unsigned int* dst = WP + (size_t)blockIdx.x * 8192;
  for (int t = threadIdx.x; t < 8192; t += 256) {
    const int p = t >> 7, jj = t & 127;
    dst[t] = packh2(src[(2 * p) * 128 + jj], src[(2 * p + 1) * 128 + jj]);
  }
}

// ---------------- table transforms: one 128-col segment per block, MFMA f16 ----------------
__global__ __launch_bounds__(256, 2) void gemm_tab1_kernel(
    const float* __restrict__ q_tab, const float* __restrict__ c_tab,
    const float* __restrict__ sd_tab, const float* __restrict__ qd_tab,
    const float* __restrict__ a_tab,
    const float* __restrict__ W4, const float* __restrict__ W5, const float* __restrict__ W6,
    const float* __restrict__ b4, const float* __restrict__ b5, const float* __restrict__ b6,
    char* __restrict__ ws) {
  __shared__ _Float16 BT[128][136];
  __shared__ _Float16 At[32][136];
  __shared__ float biasL[128];

  const float* W12 = (const float*)(ws + OFF_W12);
  const float* W13 = (const float*)(ws + OFF_W13);
  const float* bv2f = (const float*)(ws + OFF_BV2);
  const float* bv3f = (const float*)(ws + OFF_BV3);

  const int bid = blockIdx.x, tid = threadIdx.x;
  const int wv = tid >> 6, ln = tid & 63;

  int task, rb;
  if      (bid < 79)  { task = 0;  rb = bid; }
  else if (bid < 158) { task = 1;  rb = bid - 79; }
  else if (bid < 161) { task = 2;  rb = bid - 158; }
  else if (bid < 164) { task = 3;  rb = bid - 161; }
  else if (bid < 166) { task = 4;  rb = bid - 164; }
  else if (bid < 168) { task = 5;  rb = bid - 166; }
  else if (bid < 170) { task = 6;  rb = bid - 168; }
  else if (bid < 172) { task = 7;  rb = bid - 170; }
  else if (bid < 174) { task = 8;  rb = bid - 172; }
  else if (bid < 176) { task = 9;  rb = bid - 174; }
  else if (bid < 333) { task = 10; rb = bid - 176; }
  else if (bid < 490) { task = 11; rb = bid - 333; }
  else                { task = 12; rb = bid - 490; }

  // MODE: 0 = pair-packed (colmap = (c>>1)*4 + (c&1)*2 + SLOT)
  //       1 = float4     (colmap = c*4 + SLOT)
  //       2 = plain      (colmap = c)
  const float* src; int rows; const float* Bsrc; const float* bias;
  float* dst; int STR, MODE, SLOT;
  switch (task) {
    case 0:  src = q_tab;  rows = 10001; Bsrc = W12;           bias = bv2f;    dst = (float*)(ws + OFF_TQ);   STR = 256; MODE = 0; SLOT = 0; break;
    case 1:  src = q_tab;  rows = 10001; Bsrc = W13;           bias = bv3f;    dst = (float*)(ws + OFF_TQ);   STR = 256; MODE = 0; SLOT = 1; break;
    case 2:  src = c_tab;  rows = 301;   Bsrc = W12 + 128*128; bias = nullptr; dst = (float*)(ws + OFF_TC);   STR = 256; MODE = 0; SLOT = 0; break;
    case 3:  src = c_tab;  rows = 301;   Bsrc = W13 + 128*128; bias = nullptr; dst = (float*)(ws + OFF_TC);   STR = 256; MODE = 0; SLOT = 1; break;
    case 4:  src = sd_tab; rows = 200;   Bsrc = W12 + 256*128; bias = nullptr; dst = (float*)(ws + OFF_TSD);  STR = 512; MODE = 1; SLOT = 0; break;
    case 5:  src = sd_tab; rows = 200;   Bsrc = W13 + 256*128; bias = nullptr; dst = (float*)(ws + OFF_TSD);  STR = 512; MODE = 1; SLOT = 1; break;
    case 6:  src = sd_tab; rows = 200;   Bsrc = W6  + 256*128; bias = nullptr; dst = (float*)(ws + OFF_TSD);  STR = 512; MODE = 1; SLOT = 2; break;
    case 7:  src = qd_tab; rows = 200;   Bsrc = W12 + 384*128; bias = nullptr; dst = (float*)(ws + OFF_TQD);  STR = 512; MODE = 1; SLOT = 0; break;
    case 8:  src = qd_tab; rows = 200;   Bsrc = W13 + 384*128; bias = nullptr; dst = (float*)(ws + OFF_TQD);  STR = 512; MODE = 1; SLOT = 1; break;
    case 9:  src = qd_tab; rows = 200;   Bsrc = W6  + 384*128; bias = nullptr; dst = (float*)(ws + OFF_TQD);  STR = 512; MODE = 1; SLOT = 2; break;
    case 10: src = a_tab;  rows = 20002; Bsrc = W4  + 128*128; bias = b4;      dst = (float*)(ws + OFF_TA45); STR = 256; MODE = 0; SLOT = 0; break;
    case 11: src = a_tab;  rows = 20002; Bsrc = W5  + 128*128; bias = b5;      dst = (float*)(ws + OFF_TA45); STR = 256; MODE = 0; SLOT = 1; break;
    default: src = a_tab;  rows = 20002; Bsrc = W6  + 128*128; bias = b6;      dst = (float*)(ws + OFF_TA6);  STR = 128; MODE = 2; SLOT = 0; break;
  }

  // ---- stage B^T (f16) ----
#pragma unroll
  for (int r = 0; r < 8; r++) {
    const int k = (tid >> 4) + r * 16;
    const int j0 = (tid & 15) * 8;
    float4 v0 = *(const float4*)(Bsrc + k * 128 + j0);
    float4 v1 = *(const float4*)(Bsrc + k * 128 + j0 + 4);
    BT[j0 + 0][k] = (_Float16)v0.x; BT[j0 + 1][k] = (_Float16)v0.y;
    BT[j0 + 2][k] = (_Float16)v0.z; BT[j0 + 3][k] = (_Float16)v0.w;
    BT[j0 + 4][k] = (_Float16)v1.x; BT[j0 + 5][k] = (_Float16)v1.y;
    BT[j0 + 6][k] = (_Float16)v1.z; BT[j0 + 7][k] = (_Float16)v1.w;
  }
  if (tid < 128) biasL[tid] = bias ? bias[tid] : 0.0f;
  __syncthreads();

  f16x8 bfr[2][4];
#pragma unroll
  for (int ct = 0; ct < 2; ct++)
#pragma unroll
    for (int kt = 0; kt < 4; kt++) {
      const int col = wv * 32 + ct * 16 + (ln & 15);
      const int k = kt * 32 + (ln >> 4) * 8;
      bfr[ct][kt] = *(const f16x8*)&BT[col][k];
    }
  float bvl[2] = { biasL[wv * 32 + (ln & 15)], biasL[wv * 32 + 16 + (ln & 15)] };

  const int row_base = rb * 128;
  for (int ch = 0; ch < 4; ch++) {
    const int row0 = row_base + ch * 32;
    {
      const int r = tid >> 3, cb = (tid & 7) * 16;
      int sr = row0 + r; if (sr >= rows) sr = rows - 1;
      const float4* s4 = (const float4*)(src + (size_t)sr * 128 + cb);
      float4 v0 = s4[0], v1 = s4[1], v2 = s4[2], v3 = s4[3];
      f16x8 lo, hi;
      lo[0] = (_Float16)v0.x; lo[1] = (_Float16)v0.y; lo[2] = (_Float16)v0.z; lo[3] = (_Float16)v0.w;
      lo[4] = (_Float16)v1.x; lo[5] = (_Float16)v1.y; lo[6] = (_Float16)v1.z; lo[7] = (_Float16)v1.w;
      hi[0] = (_Float16)v2.x; hi[1] = (_Float16)v2.y; hi[2] = (_Float16)v2.z; hi[3] = (_Float16)v2.w;
      hi[4] = (_Float16)v3.x; hi[5] = (_Float16)v3.y; hi[6] = (_Float16)v3.z; hi[7] = (_Float16)v3.w;
      *(f16x8*)&At[r][cb] = lo;
      *(f16x8*)&At[r][cb + 8] = hi;
    }
    __syncthreads();
    f16x8 af[2][4];
#pragma unroll
    for (int rt = 0; rt < 2; rt++)
#pragma unroll
      for (int kt = 0; kt < 4; kt++) {
        const int row = rt * 16 + (ln & 15);
        const int k = kt * 32 + (ln >> 4) * 8;
        af[rt][kt] = *(const f16x8*)&At[row][k];
      }
    f32x4 acc[2][2];
#pragma unroll
    for (int rt = 0; rt < 2; rt++)
#pragma unroll
      for (int ct = 0; ct < 2; ct++) acc[rt][ct] = (f32x4){0.f, 0.f, 0.f, 0.f};
#pragma unroll
    for (int kt = 0; kt < 4; kt++)
#pragma unroll
      for (int ct = 0; ct < 2; ct++)
#pragma unroll
        for (int rt = 0; rt < 2; rt++)
          acc[rt][ct] = __builtin_amdgcn_mfma_f32_16x16x32_f16(af[rt][kt], bfr[ct][kt], acc[rt][ct], 0, 0, 0);
#pragma unroll
    for (int ct = 0; ct < 2; ct++) {
      const int col = wv * 32 + ct * 16 + (ln & 15);
      const int cm = (MODE == 0) ? (((col >> 1) << 2) + ((col & 1) << 1) + SLOT)
                   : (MODE == 1) ? ((col << 2) + SLOT) : col;
      const float bv = bvl[ct];
#pragma unroll
      for (int rt = 0; rt < 2; rt++)
#pragma unroll
        for (int e = 0; e < 4; e++) {
          const int row = row0 + rt * 16 + (ln >> 4) * 4 + e;
          if (row < rows) dst[(size_t)row * STR + cm] = acc[rt][ct][e] + bv;
        }
    }
    __syncthreads();
  }
}

// ---------------- scan: 1 block/batch, 128 thr (2 waves), FULL-K per lane ----------------
// Lane j owns output feature j end-to-end: no split-K, no shfl combines.
// 320 weight VGPRs pinned via amdgpu_waves_per_eu(1,1) -> 512-reg budget, no spill.
// 2 raw barriers/step (sdft broadcast, k broadcast); depth-2 gather prefetch.

#define PREFETCH(S, P) do {                                                   \
    int _s = (S);                                                             \
    int _qi = __builtin_amdgcn_readfirstlane(idxb[0][_s]);                    \
    int _ci = __builtin_amdgcn_readfirstlane(idxb[1][_s]);                    \
    int _si = __builtin_amdgcn_readfirstlane(idxb[2][_s]);                    \
    int _di = __builtin_amdgcn_readfirstlane(idxb[3][_s]);                    \
    int _ai = __builtin_amdgcn_readfirstlane(idxb[4][_s]);                    \
    P##q  = *(const float2*)(Tq   + ((size_t)_qi << 8) + (j << 1));           \
    P##c  = *(const float2*)(Tc   + ((size_t)_ci << 8) + (j << 1));           \
    P##s  = *(const float4*)(Ts   + ((size_t)_si << 9) + (j << 2));           \
    P##d  = *(const float4*)(Td   + ((size_t)_di << 9) + (j << 2));           \
    P##a  = *(const float2*)(Ta45 + ((size_t)_ai << 8) + (j << 1));           \
    P##a6 = Ta6[((size_t)_ai << 7) + j];                                      \
  } while (0)

#define SCAN_STEP(P, S2, L) do {                                              \
    /* stage A: full-K dots k@W2, k@W3, k@W6 (rolling kpair read) */          \
    float u2a = 0.f, u2b = 0.f, u3a = 0.f, u3b = 0.f, u6a = 0.f, u6b = 0.f;   \
    {                                                                         \
      const uint4* kp4 = (const uint4*)kpair;                                 \
      _Pragma("unroll")                                                       \
      for (int i = 0; i < 16; i++) {                                          \
        uint4 kv = kp4[i];                                                    \
        u2a = fdot2f(kv.x, w2[4 * i + 0], u2a);                               \
        u3a = fdot2f(kv.x, w3[4 * i + 0], u3a);                               \
        u6a = fdot2f(kv.x, w6[4 * i + 0], u6a);                               \
        u2b = fdot2f(kv.y, w2[4 * i + 1], u2b);                               \
        u3b = fdot2f(kv.y, w3[4 * i + 1], u3b);                               \
        u6b = fdot2f(kv.y, w6[4 * i + 1], u6b);                               \
        u2a = fdot2f(kv.z, w2[4 * i + 2], u2a);                               \
        u3a = fdot2f(kv.z, w3[4 * i + 2], u3a);                               \
        u6a = fdot2f(kv.z, w6[4 * i + 2], u6a);                               \
        u2b = fdot2f(kv.w, w2[4 * i + 3], u2b);                               \
        u3b = fdot2f(kv.w, w3[4 * i + 3], u3b);                               \
        u6b = fdot2f(kv.w, w6[4 * i + 3], u6b);                               \
      }                                                                       \
    }                                                                         \
    float U2 = (P##q.x + P##c.x + P##s.x + P##d.x) - (u2a + u2b);             \
    float U3 = (P##q.y + P##c.y + P##s.y + P##d.y) - (u3a + u3b);             \
    float U6 = (P##a6 + P##s.z + P##d.z) + (u6a + u6b);                       \
    float sdft = fsig(U2) * ftanh(U3);                                        \
    float g_ = fsig(U6);                                                      \
    ((_Float16*)sdfp)[j] = (_Float16)sdft;                                    \
    BARRIER_RAW(); /* B1: sdft broadcast */                                   \
    /* stage B: full-K dots SDFt@W4, SDFt@W5 */                               \
    float u4a = 0.f, u4b = 0.f, u5a = 0.f, u5b = 0.f;                         \
    {                                                                         \
      const uint4* sp4 = (const uint4*)sdfp;                                  \
      _Pragma("unroll")                                                       \
      for (int i = 0; i < 16; i++) {                                          \
        uint4 sv = sp4[i];                                                    \
        u4a = fdot2f(sv.x, w4[4 * i + 0], u4a);                               \
        u5a = fdot2f(sv.x, w5[4 * i + 0], u5a);                               \
        u4b = fdot2f(sv.y, w4[4 * i + 1], u4b);                               \
        u5b = fdot2f(sv.y, w5[4 * i + 1], u5b);                               \
        u4a = fdot2f(sv.z, w4[4 * i + 2], u4a);                               \
        u5a = fdot2f(sv.z, w5[4 * i + 2], u5a);                               \
        u4b = fdot2f(sv.w, w4[4 * i + 3], u4b);                               \
        u5b = fdot2f(sv.w, w5[4 * i + 3], u5b);                               \
      }                                                                       \
    }                                                                         \
    float pk = fsig(u4a + u4b + P##a.x) * ftanh(u5a + u5b + P##a.y);          \
    k = g_ * k + (1.0f - g_) * pk;                                            \
    ((_Float16*)kpair)[j] = (_Float16)k;                                      \
    Kout[((size_t)(base + (L))) * 128 + j] = k;                               \
    PREFETCH(S2, P);                                                          \
    BARRIER_RAW(); /* B2: k broadcast */                                      \
  } while (0)

__global__ __attribute__((amdgpu_flat_work_group_size(128, 128), amdgpu_waves_per_eu(1, 1)))
void scan_kernel(
    const int* __restrict__ q, const int* __restrict__ c, const int* __restrict__ sd,
    const int* __restrict__ qd, const int* __restrict__ a,
    const float* __restrict__ knowledge, char* __restrict__ ws) {
  const int j = threadIdx.x;          // feature 0..127
  const int b = blockIdx.x;
  const int base = b * L_SEQ;

  const float* Tq   = (const float*)(ws + OFF_TQ);
  const float* Tc   = (const float*)(ws + OFF_TC);
  const float* Ts   = (const float*)(ws + OFF_TSD);
  const float* Td   = (const float*)(ws + OFF_TQD);
  const float* Ta45 = (const float*)(ws + OFF_TA45);
  const float* Ta6  = (const float*)(ws + OFF_TA6);
  const unsigned int* WP = (const unsigned int*)(ws + OFF_WP);
  float* Kout = (float*)(ws + OFF_K);

  __shared__ int idxb[5][L_SEQ];                    // 10 KB
  __shared__ __align__(16) unsigned int kpair[64];  // k as f16 pairs (128 f16)
  __shared__ __align__(16) unsigned int sdfp[64];   // SDFt as f16 pairs

  // preload indices: each thread loads 4 per table
#pragma unroll
  for (int t = 0; t < 5; t++) {
    const int* src = (t == 0) ? q : (t == 1) ? c : (t == 2) ? sd : (t == 3) ? qd : a;
#pragma unroll
    for (int r = 0; r < 4; r++) idxb[t][j + 128 * r] = src[base + j + 128 * r];
  }

  // full weight columns as f16 pairs: 64 regs per matrix, 320 total
  unsigned int w2[64], w3[64], w4[64], w5[64], w6[64];
#pragma unroll
  for (int p = 0; p < 64; p++) {
    w2[p] = WP[p * 128 + j];
    w3[p] = WP[8192 + p * 128 + j];
    w4[p] = WP[2 * 8192 + p * 128 + j];
    w5[p] = WP[3 * 8192 + p * 128 + j];
    w6[p] = WP[4 * 8192 + p * 128 + j];
  }

  float k = knowledge[j];
  ((_Float16*)kpair)[j] = (_Float16)k;
  __syncthreads();

  float2 gAq, gAc, gAa; float4 gAs, gAd; float gAa6;
  float2 gBq, gBc, gBa; float4 gBs, gBd; float gBa6;
  PREFETCH(0, gA);
  PREFETCH(1, gB);

#pragma unroll 1
  for (int m = 0; m < L_SEQ / 2; m++) {
    const int l0 = 2 * m;
    const int s2 = (l0 + 2 < L_SEQ) ? (l0 + 2) : (L_SEQ - 1);
    const int s3 = (l0 + 3 < L_SEQ) ? (l0 + 3) : (L_SEQ - 1);
    SCAN_STEP(gA, s2, l0);
    SCAN_STEP(gB, s3, l0 + 1);
  }
}

// ---------------- logits head ----------------
__global__ __launch_bounds__(256, 2) void logits_kernel(
    const float* __restrict__ Wf, const float* __restrict__ bf,
    const char* __restrict__ ws, float* __restrict__ out) {
  __shared__ float WfL[1280];
  __shared__ float bfL[10];
  const int tid = threadIdx.x;
  for (int i = tid; i < 1280; i += 256) WfL[i] = Wf[i];
  if (tid < 10) bfL[tid] = bf[tid];
  __syncthreads();
  const float* K = (const float*)(ws + OFF_K);
  const int nrows = B_SZ * L_SEQ;
  for (int r = blockIdx.x * 256 + tid; r < nrows; r += gridDim.x * 256) {
    const float4* kr = (const float4*)(K + (size_t)r * 128);
    float acc[10];
#pragma unroll
    for (int i = 0; i < 10; i++) acc[i] = bfL[i];
#pragma unroll
    for (int t4 = 0; t4 < 32; t4++) {
      float4 v = kr[t4];
#pragma unroll
      for (int i = 0; i < 10; i++)
        acc[i] += v.x * WfL[(4 * t4 + 0) * 10 + i] + v.y * WfL[(4 * t4 + 1) * 10 + i] +
                  v.z * WfL[(4 * t4 + 2) * 10 + i] + v.w * WfL[(4 * t4 + 3) * 10 + i];
    }
    float* o = out + (size_t)r * 10;
#pragma unroll
    for (int i = 0; i < 10; i++) o[i] = fsig(acc[i]);
  }
}

extern "C" void kernel_launch(void* const* d_in, const int* in_sizes, int n_in,
                              void* d_out, int out_size, void* d_ws, size_t ws_size,
                              hipStream_t stream) {
  const int* q  = (const int*)d_in[0];
  const int* c  = (const int*)d_in[1];
  const int* sd = (const int*)d_in[2];
  const int* qd = (const int*)d_in[3];
  const int* a  = (const int*)d_in[4];
  const float* knowledge = (const float*)d_in[9];
  const float* q_tab  = (const float*)d_in[10];
  const float* c_tab  = (const float*)d_in[11];
  const float* sd_tab = (const float*)d_in[12];
  const float* qd_tab = (const float*)d_in[13];
  const float* a_tab  = (const float*)d_in[14];
  const float* W1 = (const float*)d_in[15];
  const float* b1 = (const float*)d_in[16];
  const float* W2 = (const float*)d_in[17];
  const float* b2 = (const float*)d_in[18];
  const float* W3 = (const float*)d_in[19];
  const float* b3 = (const float*)d_in[20];
  const float* W4 = (const float*)d_in[21];
  const float* b4 = (const float*)d_in[22];
  const float* W5 = (const float*)d_in[23];
  const float* b5 = (const float*)d_in[24];
  const float* W6 = (const float*)d_in[25];
  const float* b6 = (const float*)d_in[26];
  const float* Wf = (const float*)d_in[27];
  const float* bf = (const float*)d_in[28];
  char* ws = (char*)d_ws;
  float* out = (float*)d_out;

  prepA_kernel<<<513, 256, 0, stream>>>(W1, W2, W3, b1, b2, b3, ws);
  prepW_kernel<<<5, 256, 0, stream>>>(W2, W3, W4, W5, W6, ws);
  gemm_tab1_kernel<<<647, 256, 0, stream>>>(q_tab, c_tab, sd_tab, qd_tab, a_tab,
                                            W4, W5, W6, b4, b5, b6, ws);
  scan_kernel<<<B_SZ, 128, 0, stream>>>(q, c, sd, qd, a, knowledge, ws);
  logits_kernel<<<256, 256, 0, stream>>>(Wf, bf, ws, out);
}

// Round 7
// 873.754 us; speedup vs baseline: 1.5308x; 1.5308x over previous
//
#include <hip/hip_runtime.h>
#include <hip/hip_bf16.h>
#include <stdint.h>

#define E_DIM 128
#define L_SEQ 512
#define B_SZ  128

typedef _Float16 h2 __attribute__((ext_vector_type(2)));
typedef _Float16 f16x8 __attribute__((ext_vector_type(8)));
typedef float f32x4 __attribute__((ext_vector_type(4)));

// ---------------- workspace layout (bytes) ----------------
constexpr size_t SZ_W12  = 512 * 128 * 4;
constexpr size_t SZ_TQ   = (size_t)10001 * 128 * 2 * 4;   // (q2,q3) pairs
constexpr size_t SZ_TC   = (size_t)301 * 128 * 2 * 4;
constexpr size_t SZ_TSD  = (size_t)200 * 128 * 4 * 4;     // (sd2,sd3,sd6,pad)
constexpr size_t SZ_TQD  = (size_t)200 * 128 * 4 * 4;
constexpr size_t SZ_TA45 = (size_t)20002 * 128 * 2 * 4;   // (a4,a5)
constexpr size_t SZ_TA6  = (size_t)20002 * 128 * 4;
constexpr size_t SZ_K    = (size_t)B_SZ * L_SEQ * 128 * 4;
constexpr size_t SZ_WP   = (size_t)5 * 64 * 128 * 4;      // packed f16-pair weights

constexpr size_t OFF_W12  = 0;
constexpr size_t OFF_W13  = OFF_W12 + SZ_W12;
constexpr size_t OFF_BV2  = OFF_W13 + SZ_W12;
constexpr size_t OFF_BV3  = OFF_BV2 + 512;
constexpr size_t OFF_TQ   = OFF_BV3 + 512;
constexpr size_t OFF_TC   = OFF_TQ + SZ_TQ;
constexpr size_t OFF_TSD  = OFF_TC + SZ_TC;
constexpr size_t OFF_TQD  = OFF_TSD + SZ_TSD;
constexpr size_t OFF_TA45 = OFF_TQD + SZ_TQD;
constexpr size_t OFF_TA6  = OFF_TA45 + SZ_TA45;
constexpr size_t OFF_K    = OFF_TA6 + SZ_TA6;
constexpr size_t OFF_WP   = OFF_K + SZ_K;

// ---------------- helpers ----------------
__device__ __forceinline__ float fdot2f(unsigned int a, unsigned int b, float c) {
#if __has_builtin(__builtin_amdgcn_fdot2)
  return __builtin_amdgcn_fdot2(__builtin_bit_cast(h2, a), __builtin_bit_cast(h2, b), c, false);
#else
  h2 x = __builtin_bit_cast(h2, a), y = __builtin_bit_cast(h2, b);
  return c + (float)x[0] * (float)y[0] + (float)x[1] * (float)y[1];
#endif
}

__device__ __forceinline__ unsigned int packh2(float a, float b) {
  h2 v; v[0] = (_Float16)a; v[1] = (_Float16)b;
  return __builtin_bit_cast(unsigned int, v);
}

__device__ __forceinline__ float fsig(float x) {
  float t = __builtin_amdgcn_exp2f(-1.4426950408889634f * x);
  return __builtin_amdgcn_rcpf(1.0f + t);
}
__device__ __forceinline__ float ftanh(float x) {
  float t = __builtin_amdgcn_exp2f(2.8853900817779268f * x);
  return 1.0f - 2.0f * __builtin_amdgcn_rcpf(t + 1.0f);
}

// LDS-only barrier: no vmcnt drain -> global prefetch stays in flight
#define BARRIER_RAW() asm volatile("s_waitcnt lgkmcnt(0)\n\ts_barrier" ::: "memory")

// ---------------- prep A: W12 = W1@W2, W13 = W1@W3 (2 rows/block) ----------------
__global__ __launch_bounds__(256, 2) void prepA_kernel(
    const float* __restrict__ W1, const float* __restrict__ W2, const float* __restrict__ W3,
    const float* __restrict__ b1, const float* __restrict__ b2, const float* __restrict__ b3,
    char* __restrict__ ws) {
  float* W12 = (float*)(ws + OFF_W12);
  float* W13 = (float*)(ws + OFF_W13);
  float* bv2 = (float*)(ws + OFF_BV2);
  float* bv3 = (float*)(ws + OFF_BV3);
  const int blk = blockIdx.x, tid = threadIdx.x;
  if (blk < 512) {
    const int m = blk >> 8;
    const int rp = blk & 255;
    const float* M = m ? W3 : W2;
    float* dst = m ? W13 : W12;
    const int rr = tid >> 7, j = tid & 127;
    const int r = rp * 2 + rr;
    __shared__ float rowL[2][128];
    rowL[rr][j] = W1[r * 128 + j];
    __syncthreads();
    float acc = 0.0f;
#pragma unroll 8
    for (int t = 0; t < 128; t++) acc += rowL[rr][t] * M[t * 128 + j];
    dst[r * 128 + j] = acc;
  } else if (tid < 128) {
    float a2 = b2[tid], a3 = b3[tid];
    for (int t = 0; t < 128; t++) {
      float bb = b1[t];
      a2 += bb * W2[t * 128 + tid];
      a3 += bb * W3[t * 128 + tid];
    }
    bv2[tid] = a2;
    bv3[tid] = a3;
  }
}

// ---------------- prep W: pack weight columns into f16-pair tables ----------------
// WP[mat][p][j] = packh2(W[2p][j], W[2p+1][j]); mat order: W2,W3,W4,W5,W6
__global__ __launch_bounds__(256, 2) void prepW_kernel(
    const float* __restrict__ W2, const float* __restrict__ W3, const float* __restrict__ W4,
    const float* __restrict__ W5, const float* __restrict__ W6, char* __restrict__ ws) {
  unsigned int* WP = (unsigned int*)(ws + OFF_WP);
  const float* src = (blockIdx.x == 0) ? W2 : (blockIdx.x == 1) ? W3 :
                     (blockIdx.x == 2) ? W4 : (blockIdx.x == 3) ? W5 : W6;
  unsigned int* dst = WP + (size_t)blockIdx.x * 8192;
  for (int t = threadIdx.x; t < 8192; t += 256) {
    const int p = t >> 7, jj = t & 127;
    dst[t] = packh2(src[(2 * p) * 128 + jj], src[(2 * p + 1) * 128 + jj]);
  }
}

// ---------------- table transforms: one 128-col segment per block, MFMA f16 ----------------
__global__ __launch_bounds__(256, 2) void gemm_tab1_kernel(
    const float* __restrict__ q_tab, const float* __restrict__ c_tab,
    const float* __restrict__ sd_tab, const float* __restrict__ qd_tab,
    const float* __restrict__ a_tab,
    const float* __restrict__ W4, const float* __restrict__ W5, const float* __restrict__ W6,
    const float* __restrict__ b4, const float* __restrict__ b5, const float* __restrict__ b6,
    char* __restrict__ ws) {
  __shared__ _Float16 BT[128][136];
  __shared__ _Float16 At[32][136];
  __shared__ float biasL[128];

  const float* W12 = (const float*)(ws + OFF_W12);
  const float* W13 = (const float*)(ws + OFF_W13);
  const float* bv2f = (const float*)(ws + OFF_BV2);
  const float* bv3f = (const float*)(ws + OFF_BV3);

  const int bid = blockIdx.x, tid = threadIdx.x;
  const int wv = tid >> 6, ln = tid & 63;

  int task, rb;
  if      (bid < 79)  { task = 0;  rb = bid; }
  else if (bid < 158) { task = 1;  rb = bid - 79; }
  else if (bid < 161) { task = 2;  rb = bid - 158; }
  else if (bid < 164) { task = 3;  rb = bid - 161; }
  else if (bid < 166) { task = 4;  rb = bid - 164; }
  else if (bid < 168) { task = 5;  rb = bid - 166; }
  else if (bid < 170) { task = 6;  rb = bid - 168; }
  else if (bid < 172) { task = 7;  rb = bid - 170; }
  else if (bid < 174) { task = 8;  rb = bid - 172; }
  else if (bid < 176) { task = 9;  rb = bid - 174; }
  else if (bid < 333) { task = 10; rb = bid - 176; }
  else if (bid < 490) { task = 11; rb = bid - 333; }
  else                { task = 12; rb = bid - 490; }

  const float* src; int rows; const float* Bsrc; const float* bias;
  float* dst; int STR, MODE, SLOT;
  switch (task) {
    case 0:  src = q_tab;  rows = 10001; Bsrc = W12;           bias = bv2f;    dst = (float*)(ws + OFF_TQ);   STR = 256; MODE = 0; SLOT = 0; break;
    case 1:  src = q_tab;  rows = 10001; Bsrc = W13;           bias = bv3f;    dst = (float*)(ws + OFF_TQ);   STR = 256; MODE = 0; SLOT = 1; break;
    case 2:  src = c_tab;  rows = 301;   Bsrc = W12 + 128*128; bias = nullptr; dst = (float*)(ws + OFF_TC);   STR = 256; MODE = 0; SLOT = 0; break;
    case 3:  src = c_tab;  rows = 301;   Bsrc = W13 + 128*128; bias = nullptr; dst = (float*)(ws + OFF_TC);   STR = 256; MODE = 0; SLOT = 1; break;
    case 4:  src = sd_tab; rows = 200;   Bsrc = W12 + 256*128; bias = nullptr; dst = (float*)(ws + OFF_TSD);  STR = 512; MODE = 1; SLOT = 0; break;
    case 5:  src = sd_tab; rows = 200;   Bsrc = W13 + 256*128; bias = nullptr; dst = (float*)(ws + OFF_TSD);  STR = 512; MODE = 1; SLOT = 1; break;
    case 6:  src = sd_tab; rows = 200;   Bsrc = W6  + 256*128; bias = nullptr; dst = (float*)(ws + OFF_TSD);  STR = 512; MODE = 1; SLOT = 2; break;
    case 7:  src = qd_tab; rows = 200;   Bsrc = W12 + 384*128; bias = nullptr; dst = (float*)(ws + OFF_TQD);  STR = 512; MODE = 1; SLOT = 0; break;
    case 8:  src = qd_tab; rows = 200;   Bsrc = W13 + 384*128; bias = nullptr; dst = (float*)(ws + OFF_TQD);  STR = 512; MODE = 1; SLOT = 1; break;
    case 9:  src = qd_tab; rows = 200;   Bsrc = W6  + 384*128; bias = nullptr; dst = (float*)(ws + OFF_TQD);  STR = 512; MODE = 1; SLOT = 2; break;
    case 10: src = a_tab;  rows = 20002; Bsrc = W4  + 128*128; bias = b4;      dst = (float*)(ws + OFF_TA45); STR = 256; MODE = 0; SLOT = 0; break;
    case 11: src = a_tab;  rows = 20002; Bsrc = W5  + 128*128; bias = b5;      dst = (float*)(ws + OFF_TA45); STR = 256; MODE = 0; SLOT = 1; break;
    default: src = a_tab;  rows = 20002; Bsrc = W6  + 128*128; bias = b6;      dst = (float*)(ws + OFF_TA6);  STR = 128; MODE = 2; SLOT = 0; break;
  }

  // ---- stage B^T (f16) ----
#pragma unroll
  for (int r = 0; r < 8; r++) {
    const int k = (tid >> 4) + r * 16;
    const int j0 = (tid & 15) * 8;
    float4 v0 = *(const float4*)(Bsrc + k * 128 + j0);
    float4 v1 = *(const float4*)(Bsrc + k * 128 + j0 + 4);
    BT[j0 + 0][k] = (_Float16)v0.x; BT[j0 + 1][k] = (_Float16)v0.y;
    BT[j0 + 2][k] = (_Float16)v0.z; BT[j0 + 3][k] = (_Float16)v0.w;
    BT[j0 + 4][k] = (_Float16)v1.x; BT[j0 + 5][k] = (_Float16)v1.y;
    BT[j0 + 6][k] = (_Float16)v1.z; BT[j0 + 7][k] = (_Float16)v1.w;
  }
  if (tid < 128) biasL[tid] = bias ? bias[tid] : 0.0f;
  __syncthreads();

  f16x8 bfr[2][4];
#pragma unroll
  for (int ct = 0; ct < 2; ct++)
#pragma unroll
    for (int kt = 0; kt < 4; kt++) {
      const int col = wv * 32 + ct * 16 + (ln & 15);
      const int k = kt * 32 + (ln >> 4) * 8;
      bfr[ct][kt] = *(const f16x8*)&BT[col][k];
    }
  float bvl[2] = { biasL[wv * 32 + (ln & 15)], biasL[wv * 32 + 16 + (ln & 15)] };

  const int row_base = rb * 128;
  for (int ch = 0; ch < 4; ch++) {
    const int row0 = row_base + ch * 32;
    {
      const int r = tid >> 3, cb = (tid & 7) * 16;
      int sr = row0 + r; if (sr >= rows) sr = rows - 1;
      const float4* s4 = (const float4*)(src + (size_t)sr * 128 + cb);
      float4 v0 = s4[0], v1 = s4[1], v2 = s4[2], v3 = s4[3];
      f16x8 lo, hi;
      lo[0] = (_Float16)v0.x; lo[1] = (_Float16)v0.y; lo[2] = (_Float16)v0.z; lo[3] = (_Float16)v0.w;
      lo[4] = (_Float16)v1.x; lo[5] = (_Float16)v1.y; lo[6] = (_Float16)v1.z; lo[7] = (_Float16)v1.w;
      hi[0] = (_Float16)v2.x; hi[1] = (_Float16)v2.y; hi[2] = (_Float16)v2.z; hi[3] = (_Float16)v2.w;
      hi[4] = (_Float16)v3.x; hi[5] = (_Float16)v3.y; hi[6] = (_Float16)v3.z; hi[7] = (_Float16)v3.w;
      *(f16x8*)&At[r][cb] = lo;
      *(f16x8*)&At[r][cb + 8] = hi;
    }
    __syncthreads();
    f16x8 af[2][4];
#pragma unroll
    for (int rt = 0; rt < 2; rt++)
#pragma unroll
      for (int kt = 0; kt < 4; kt++) {
        const int row = rt * 16 + (ln & 15);
        const int k = kt * 32 + (ln >> 4) * 8;
        af[rt][kt] = *(const f16x8*)&At[row][k];
      }
    f32x4 acc[2][2];
#pragma unroll
    for (int rt = 0; rt < 2; rt++)
#pragma unroll
      for (int ct = 0; ct < 2; ct++) acc[rt][ct] = (f32x4){0.f, 0.f, 0.f, 0.f};
#pragma unroll
    for (int kt = 0; kt < 4; kt++)
#pragma unroll
      for (int ct = 0; ct < 2; ct++)
#pragma unroll
        for (int rt = 0; rt < 2; rt++)
          acc[rt][ct] = __builtin_amdgcn_mfma_f32_16x16x32_f16(af[rt][kt], bfr[ct][kt], acc[rt][ct], 0, 0, 0);
#pragma unroll
    for (int ct = 0; ct < 2; ct++) {
      const int col = wv * 32 + ct * 16 + (ln & 15);
      const int cm = (MODE == 0) ? (((col >> 1) << 2) + ((col & 1) << 1) + SLOT)
                   : (MODE == 1) ? ((col << 2) + SLOT) : col;
      const float bv = bvl[ct];
#pragma unroll
      for (int rt = 0; rt < 2; rt++)
#pragma unroll
        for (int e = 0; e < 4; e++) {
          const int row = row0 + rt * 16 + (ln >> 4) * 4 + e;
          if (row < rows) dst[(size_t)row * STR + cm] = acc[rt][ct][e] + bv;
        }
    }
    __syncthreads();
  }
}

// ---------------- scan: 2 batches/block (512 thr), waves_per_eu(2,2) => 256-reg cap ----------------
// group g = tid>>8 -> batch 2*bid+g; within group: lane l of wave w:
// j = 32*w + (l&31), h = l>>5 (split-K half). Half-combine via shfl_xor(32).
// 2 raw barriers/step; packed-table gathers: 6 loads/step, depth-2 prefetch.

#define PREFETCH(S, P) do {                                                   \
    int _s = (S);                                                             \
    int _qi = __builtin_amdgcn_readfirstlane(idxb[g][0][_s]);                 \
    int _ci = __builtin_amdgcn_readfirstlane(idxb[g][1][_s]);                 \
    int _si = __builtin_amdgcn_readfirstlane(idxb[g][2][_s]);                 \
    int _di = __builtin_amdgcn_readfirstlane(idxb[g][3][_s]);                 \
    int _ai = __builtin_amdgcn_readfirstlane(idxb[g][4][_s]);                 \
    P##q  = *(const float2*)(Tq   + ((size_t)_qi << 8) + (j << 1));           \
    P##c  = *(const float2*)(Tc   + ((size_t)_ci << 8) + (j << 1));           \
    P##s  = *(const float4*)(Ts   + ((size_t)_si << 9) + (j << 2));           \
    P##d  = *(const float4*)(Td   + ((size_t)_di << 9) + (j << 2));           \
    P##a  = *(const float2*)(Ta45 + ((size_t)_ai << 8) + (j << 1));           \
    P##a6 = Ta6[((size_t)_ai << 7) + j];                                      \
  } while (0)

#define SCAN_STEP(P, S2, L) do {                                              \
    float u2a = 0.f, u2b = 0.f, u3a = 0.f, u3b = 0.f, u6a = 0.f, u6b = 0.f;   \
    {                                                                         \
      const uint4* kp4 = ((const uint4*)kpair[g]) + 8 * h;                    \
      _Pragma("unroll")                                                       \
      for (int i = 0; i < 8; i++) {                                           \
        uint4 kv = kp4[i];                                                    \
        u2a = fdot2f(kv.x, w2h[4 * i + 0], u2a);                              \
        u3a = fdot2f(kv.x, w3h[4 * i + 0], u3a);                              \
        u6a = fdot2f(kv.x, w6h[4 * i + 0], u6a);                              \
        u2b = fdot2f(kv.y, w2h[4 * i + 1], u2b);                              \
        u3b = fdot2f(kv.y, w3h[4 * i + 1], u3b);                              \
        u6b = fdot2f(kv.y, w6h[4 * i + 1], u6b);                              \
        u2a = fdot2f(kv.z, w2h[4 * i + 2], u2a);                              \
        u3a = fdot2f(kv.z, w3h[4 * i + 2], u3a);                              \
        u6a = fdot2f(kv.z, w6h[4 * i + 2], u6a);                              \
        u2b = fdot2f(kv.w, w2h[4 * i + 3], u2b);                              \
        u3b = fdot2f(kv.w, w3h[4 * i + 3], u3b);                              \
        u6b = fdot2f(kv.w, w6h[4 * i + 3], u6b);                              \
      }                                                                       \
    }                                                                         \
    float U2p = u2a + u2b, U3p = u3a + u3b, U6p = u6a + u6b;                  \
    U2p += __shfl_xor(U2p, 32);                                               \
    U3p += __shfl_xor(U3p, 32);                                               \
    U6p += __shfl_xor(U6p, 32);                                               \
    float U2 = (P##q.x + P##c.x + P##s.x + P##d.x) - U2p;                     \
    float U3 = (P##q.y + P##c.y + P##s.y + P##d.y) - U3p;                     \
    float U6 = (P##a6 + P##s.z + P##d.z) + U6p;                               \
    float sdft = fsig(U2) * ftanh(U3);                                        \
    float g_ = fsig(U6);                                                      \
    if (!h) ((_Float16*)sdfp[g])[j] = (_Float16)sdft;                         \
    BARRIER_RAW(); /* B1: sdft broadcast */                                   \
    float u4a = 0.f, u4b = 0.f, u5a = 0.f, u5b = 0.f;                         \
    {                                                                         \
      const uint4* sp4 = ((const uint4*)sdfp[g]) + 8 * h;                     \
      _Pragma("unroll")                                                       \
      for (int i = 0; i < 8; i++) {                                           \
        uint4 sv = sp4[i];                                                    \
        u4a = fdot2f(sv.x, w4h[4 * i + 0], u4a);                              \
        u5a = fdot2f(sv.x, w5h[4 * i + 0], u5a);                              \
        u4b = fdot2f(sv.y, w4h[4 * i + 1], u4b);                              \
        u5b = fdot2f(sv.y, w5h[4 * i + 1], u5b);                              \
        u4a = fdot2f(sv.z, w4h[4 * i + 2], u4a);                              \
        u5a = fdot2f(sv.z, w5h[4 * i + 2], u5a);                              \
        u4b = fdot2f(sv.w, w4h[4 * i + 3], u4b);                              \
        u5b = fdot2f(sv.w, w5h[4 * i + 3], u5b);                              \
      }                                                                       \
    }                                                                         \
    float U4p = u4a + u4b, U5p = u5a + u5b;                                   \
    U4p += __shfl_xor(U4p, 32);                                               \
    U5p += __shfl_xor(U5p, 32);                                               \
    float pk = fsig(U4p + P##a.x) * ftanh(U5p + P##a.y);                      \
    k = g_ * k + (1.0f - g_) * pk;                                            \
    if (h) ((_Float16*)kpair[g])[j] = (_Float16)k;                            \
    if (!h) Kout[((size_t)(base + (L))) * 128 + j] = k;                       \
    PREFETCH(S2, P);                                                          \
    BARRIER_RAW(); /* B2: k broadcast */                                      \
  } while (0)

__global__ __attribute__((amdgpu_flat_work_group_size(512, 512), amdgpu_waves_per_eu(2, 2)))
void scan_kernel(
    const int* __restrict__ q, const int* __restrict__ c, const int* __restrict__ sd,
    const int* __restrict__ qd, const int* __restrict__ a,
    const float* __restrict__ knowledge, char* __restrict__ ws) {
  const int tid = threadIdx.x;
  const int g = tid >> 8;
  const int t256 = tid & 255;
  const int ln = tid & 63;
  const int wvl = (t256 >> 6);
  const int j = (wvl << 5) | (ln & 31);
  const int h = ln >> 5;
  const int b = (blockIdx.x << 1) | g;
  const int base = b * L_SEQ;

  const float* Tq   = (const float*)(ws + OFF_TQ);
  const float* Tc   = (const float*)(ws + OFF_TC);
  const float* Ts   = (const float*)(ws + OFF_TSD);
  const float* Td   = (const float*)(ws + OFF_TQD);
  const float* Ta45 = (const float*)(ws + OFF_TA45);
  const float* Ta6  = (const float*)(ws + OFF_TA6);
  const unsigned int* WP = (const unsigned int*)(ws + OFF_WP);
  float* Kout = (float*)(ws + OFF_K);

  __shared__ int idxb[2][5][L_SEQ];                    // 20 KB
  __shared__ __align__(16) unsigned int kpair[2][64];
  __shared__ __align__(16) unsigned int sdfp[2][64];

  idxb[g][0][t256] = q[base + t256];  idxb[g][0][t256 + 256] = q[base + t256 + 256];
  idxb[g][1][t256] = c[base + t256];  idxb[g][1][t256 + 256] = c[base + t256 + 256];
  idxb[g][2][t256] = sd[base + t256]; idxb[g][2][t256 + 256] = sd[base + t256 + 256];
  idxb[g][3][t256] = qd[base + t256]; idxb[g][3][t256 + 256] = qd[base + t256 + 256];
  idxb[g][4][t256] = a[base + t256];  idxb[g][4][t256 + 256] = a[base + t256 + 256];

  // weight half-columns from packed WP (pairs 32h..32h+31, col j): 32 regs/matrix
  unsigned int w2h[32], w3h[32], w4h[32], w5h[32], w6h[32];
  const int p0 = 32 * h;
#pragma unroll
  for (int p = 0; p < 32; p++) {
    w2h[p] = WP[(p0 + p) * 128 + j];
    w3h[p] = WP[8192 + (p0 + p) * 128 + j];
    w4h[p] = WP[2 * 8192 + (p0 + p) * 128 + j];
    w5h[p] = WP[3 * 8192 + (p0 + p) * 128 + j];
    w6h[p] = WP[4 * 8192 + (p0 + p) * 128 + j];
  }

  float k = knowledge[j];
  if (h) ((_Float16*)kpair[g])[j] = (_Float16)k;
  __syncthreads();

  float2 gAq, gAc, gAa; float4 gAs, gAd; float gAa6;
  float2 gBq, gBc, gBa; float4 gBs, gBd; float gBa6;
  PREFETCH(0, gA);
  PREFETCH(1, gB);

#pragma unroll 1
  for (int m = 0; m < L_SEQ / 2; m++) {
    const int l0 = 2 * m;
    const int s2 = (l0 + 2 < L_SEQ) ? (l0 + 2) : (L_SEQ - 1);
    const int s3 = (l0 + 3 < L_SEQ) ? (l0 + 3) : (L_SEQ - 1);
    SCAN_STEP(gA, s2, l0);
    SCAN_STEP(gB, s3, l0 + 1);
  }
}

// ---------------- logits head ----------------
__global__ __launch_bounds__(256, 2) void logits_kernel(
    const float* __restrict__ Wf, const float* __restrict__ bf,
    const char* __restrict__ ws, float* __restrict__ out) {
  __shared__ float WfL[1280];
  __shared__ float bfL[10];
  const int tid = threadIdx.x;
  for (int i = tid; i < 1280; i += 256) WfL[i] = Wf[i];
  if (tid < 10) bfL[tid] = bf[tid];
  __syncthreads();
  const float* K = (const float*)(ws + OFF_K);
  const int nrows = B_SZ * L_SEQ;
  for (int r = blockIdx.x * 256 + tid; r < nrows; r += gridDim.x * 256) {
    const float4* kr = (const float4*)(K + (size_t)r * 128);
    float acc[10];
#pragma unroll
    for (int i = 0; i < 10; i++) acc[i] = bfL[i];
#pragma unroll
    for (int t4 = 0; t4 < 32; t4++) {
      float4 v = kr[t4];
#pragma unroll
      for (int i = 0; i < 10; i++)
        acc[i] += v.x * WfL[(4 * t4 + 0) * 10 + i] + v.y * WfL[(4 * t4 + 1) * 10 + i] +
                  v.z * WfL[(4 * t4 + 2) * 10 + i] + v.w * WfL[(4 * t4 + 3) * 10 + i];
    }
    float* o = out + (size_t)r * 10;
#pragma unroll
    for (int i = 0; i < 10; i++) o[i] = fsig(acc[i]);
  }
}

extern "C" void kernel_launch(void* const* d_in, const int* in_sizes, int n_in,
                              void* d_out, int out_size, void* d_ws, size_t ws_size,
                              hipStream_t stream) {
  const int* q  = (const int*)d_in[0];
  const int* c  = (const int*)d_in[1];
  const int* sd = (const int*)d_in[2];
  const int* qd = (const int*)d_in[3];
  const int* a  = (const int*)d_in[4];
  const float* knowledge = (const float*)d_in[9];
  const float* q_tab  = (const float*)d_in[10];
  const float* c_tab  = (const float*)d_in[11];
  const float* sd_tab = (const float*)d_in[12];
  const float* qd_tab = (const float*)d_in[13];
  const float* a_tab  = (const float*)d_in[14];
  const float* W1 = (const float*)d_in[15];
  const float* b1 = (const float*)d_in[16];
  const float* W2 = (const float*)d_in[17];
  const float* b2 = (const float*)d_in[18];
  const float* W3 = (const float*)d_in[19];
  const float* b3 = (const float*)d_in[20];
  const float* W4 = (const float*)d_in[21];
  const float* b4 = (const float*)d_in[22];
  const float* W5 = (const float*)d_in[23];
  const float* b5 = (const float*)d_in[24];
  const float* W6 = (const float*)d_in[25];
  const float* b6 = (const float*)d_in[26];
  const float* Wf = (const float*)d_in[27];
  const float* bf = (const float*)d_in[28];
  char* ws = (char*)d_ws;
  float* out = (float*)d_out;

  prepA_kernel<<<513, 256, 0, stream>>>(W1, W2, W3, b1, b2, b3, ws);
  prepW_kernel<<<5, 256, 0, stream>>>(W2, W3, W4, W5, W6, ws);
  gemm_tab1_kernel<<<647, 256, 0, stream>>>(q_tab, c_tab, sd_tab, qd_tab, a_tab,
                                            W4, W5, W6, b4, b5, b6, ws);
  scan_kernel<<<B_SZ / 2, 512, 0, stream>>>(q, c, sd, qd, a, knowledge, ws);
  logits_kernel<<<256, 256, 0, stream>>>(Wf, bf, ws, out);
}